// Round 1
// baseline (303.739 us; speedup 1.0000x reference)
//
#include <hip/hip_runtime.h>
#include <hip/hip_bf16.h>

#define BATCH  4
#define SEQ    4096
#define DMODEL 1024
#define HDIM   128
#define MROWS  (BATCH * SEQ)   // 16384

typedef __attribute__((ext_vector_type(8))) short short8;
typedef __attribute__((ext_vector_type(4))) float floatx4;

static __device__ __forceinline__ short f2bf(float f) {
    __hip_bfloat16 h = __float2bfloat16(f);
    union { __hip_bfloat16 h; short s; } u; u.h = h;
    return u.s;
}

// ---------------------------------------------------------------------------
// fp32 -> bf16 conversion (8 elems/thread), optional scale folded in.
// ---------------------------------------------------------------------------
__global__ __launch_bounds__(256) void cvt_bf16_kernel(
    const float* __restrict__ src, unsigned short* __restrict__ dst,
    int n8, float scale)
{
    int i = blockIdx.x * 256 + threadIdx.x;
    if (i >= n8) return;
    const float4* s4 = reinterpret_cast<const float4*>(src);
    float4 a = s4[2 * i];
    float4 b = s4[2 * i + 1];
    short8 o;
    o[0] = f2bf(a.x * scale); o[1] = f2bf(a.y * scale);
    o[2] = f2bf(a.z * scale); o[3] = f2bf(a.w * scale);
    o[4] = f2bf(b.x * scale); o[5] = f2bf(b.y * scale);
    o[6] = f2bf(b.z * scale); o[7] = f2bf(b.w * scale);
    reinterpret_cast<short8*>(dst)[i] = o;
}

// ---------------------------------------------------------------------------
// QKV projection: y = x @ W^T  for W = [Wq;Wk;Wv] (384 rows, q rows pre-scaled
// by 1/sqrt(H)). One block = 16 rows of x, 4 waves x 6 col-tiles of 16.
// q,k stored row-major [MROWS][128] bf16; v stored transposed [B][128][SEQ].
// MFMA 16x16x32 bf16 layouts (gfx950): A: lane l holds A[l&15][(l>>4)*8+j];
// B: lane l holds B[(l>>4)*8+j][l&15]; C/D: col=l&15, row=(l>>4)*4+reg.
// ---------------------------------------------------------------------------
__global__ __launch_bounds__(256) void qkv_kernel(
    const unsigned short* __restrict__ xbf,  // [MROWS][DMODEL]
    const unsigned short* __restrict__ wbf,  // [384][DMODEL]
    unsigned short* __restrict__ qo,         // [MROWS][HDIM]
    unsigned short* __restrict__ ko,         // [MROWS][HDIM]
    unsigned short* __restrict__ vt)         // [BATCH][HDIM][SEQ]
{
    const int m0   = blockIdx.x * 16;
    const int wave = threadIdx.x >> 6;
    const int lane = threadIdx.x & 63;
    const int lr   = lane & 15;
    const int lh   = lane >> 4;

    floatx4 acc[6];
#pragma unroll
    for (int t = 0; t < 6; ++t) acc[t] = (floatx4){0.f, 0.f, 0.f, 0.f};

    const int cbase = wave * 96;
    const unsigned short* xrow = xbf + (size_t)(m0 + lr) * DMODEL + lh * 8;

    for (int k0 = 0; k0 < DMODEL; k0 += 32) {
        short8 afrag = *reinterpret_cast<const short8*>(xrow + k0);
#pragma unroll
        for (int t = 0; t < 6; ++t) {
            const unsigned short* wrow =
                wbf + (size_t)(cbase + t * 16 + lr) * DMODEL + k0 + lh * 8;
            short8 bfrag = *reinterpret_cast<const short8*>(wrow);
            acc[t] = __builtin_amdgcn_mfma_f32_16x16x32_bf16(afrag, bfrag, acc[t], 0, 0, 0);
        }
    }

#pragma unroll
    for (int t = 0; t < 6; ++t) {
        const int c = cbase + t * 16 + lr;
#pragma unroll
        for (int r = 0; r < 4; ++r) {
            const int gm = m0 + lh * 4 + r;
            const unsigned short v = (unsigned short)f2bf(acc[t][r]);
            if (c < HDIM) {
                qo[(size_t)gm * HDIM + c] = v;
            } else if (c < 2 * HDIM) {
                ko[(size_t)gm * HDIM + (c - HDIM)] = v;
            } else {
                const int b = gm >> 12;          // / SEQ
                const int s = gm & (SEQ - 1);    // % SEQ
                vt[((size_t)b * HDIM + (c - 2 * HDIM)) * SEQ + s] = v;
            }
        }
    }
}

// ---------------------------------------------------------------------------
// Causal flash attention. 1 wave per block, 16 q-rows per wave, KV tile = 32.
// q pre-scaled by 1/sqrt(H). K/V read straight from global (L2-resident).
// Online softmax in C/D register layout; P transposed via small padded LDS.
// ---------------------------------------------------------------------------
__global__ __launch_bounds__(64) void attn_kernel(
    const unsigned short* __restrict__ qo,
    const unsigned short* __restrict__ ko,
    const unsigned short* __restrict__ vt,
    float* __restrict__ out)
{
    __shared__ __align__(16) unsigned short p_lds[16][40];  // +8 pad: bank spread

    const int bid  = blockIdx.x;
    const int b    = bid & (BATCH - 1);
    const int qt   = (SEQ / 16 - 1) - (bid >> 2);   // longest blocks dispatch first
    const int wq   = qt * 16;
    const int lane = threadIdx.x & 63;
    const int lr   = lane & 15;
    const int lh   = lane >> 4;

    const unsigned short* qb = qo + ((size_t)b * SEQ + wq) * HDIM;
    const unsigned short* kb = ko + (size_t)b * SEQ * HDIM;
    const unsigned short* vb = vt + (size_t)b * HDIM * SEQ;

    // Q A-fragments (4 frags over d=128)
    short8 qa[4];
#pragma unroll
    for (int f = 0; f < 4; ++f)
        qa[f] = *reinterpret_cast<const short8*>(qb + (size_t)lr * HDIM + f * 32 + lh * 8);

    floatx4 acco[8];
#pragma unroll
    for (int f = 0; f < 8; ++f) acco[f] = (floatx4){0.f, 0.f, 0.f, 0.f};
    float m_r[4], l_r[4];
#pragma unroll
    for (int r = 0; r < 4; ++r) { m_r[r] = -3.0e38f; l_r[r] = 0.f; }

    const int nkv = wq + 16;
    for (int kv0 = 0; kv0 < nkv; kv0 += 32) {
        // ---- scores: two 16x16 tiles over kv ----
        floatx4 s0 = (floatx4){0.f, 0.f, 0.f, 0.f};
        floatx4 s1 = (floatx4){0.f, 0.f, 0.f, 0.f};
#pragma unroll
        for (int f = 0; f < 4; ++f) {
            short8 b0 = *reinterpret_cast<const short8*>(
                kb + (size_t)(kv0 + lr) * HDIM + f * 32 + lh * 8);
            short8 b1 = *reinterpret_cast<const short8*>(
                kb + (size_t)(kv0 + 16 + lr) * HDIM + f * 32 + lh * 8);
            s0 = __builtin_amdgcn_mfma_f32_16x16x32_bf16(qa[f], b0, s0, 0, 0, 0);
            s1 = __builtin_amdgcn_mfma_f32_16x16x32_bf16(qa[f], b1, s1, 0, 0, 0);
        }
        // ---- causal mask (only diagonal tiles) ----
        if (kv0 + 31 > wq) {
#pragma unroll
            for (int r = 0; r < 4; ++r) {
                const int qi = wq + lh * 4 + r;
                if (kv0 + lr      > qi) s0[r] = -3.0e38f;
                if (kv0 + 16 + lr > qi) s1[r] = -3.0e38f;
            }
        }
        // ---- online softmax (rows live across 16-lane groups) ----
#pragma unroll
        for (int r = 0; r < 4; ++r) {
            float t = fmaxf(s0[r], s1[r]);
            t = fmaxf(t, __shfl_xor(t, 1));
            t = fmaxf(t, __shfl_xor(t, 2));
            t = fmaxf(t, __shfl_xor(t, 4));
            t = fmaxf(t, __shfl_xor(t, 8));
            const float mn  = fmaxf(m_r[r], t);
            const float fac = __expf(m_r[r] - mn);
            m_r[r] = mn;
            const float p0 = __expf(s0[r] - mn);
            const float p1 = __expf(s1[r] - mn);
            p_lds[lh * 4 + r][lr]      = (unsigned short)f2bf(p0);
            p_lds[lh * 4 + r][16 + lr] = (unsigned short)f2bf(p1);
            float ps = p0 + p1;
            ps += __shfl_xor(ps, 1);
            ps += __shfl_xor(ps, 2);
            ps += __shfl_xor(ps, 4);
            ps += __shfl_xor(ps, 8);
            l_r[r] = l_r[r] * fac + ps;
#pragma unroll
            for (int f = 0; f < 8; ++f) acco[f][r] *= fac;
        }
        // ---- PV: P (16x32) from LDS as A-frag, V^T fragments from global ----
        short8 pa = *reinterpret_cast<const short8*>(&p_lds[lr][lh * 8]);
#pragma unroll
        for (int f = 0; f < 8; ++f) {
            short8 vfrag = *reinterpret_cast<const short8*>(
                vb + (size_t)(f * 16 + lr) * SEQ + kv0 + lh * 8);
            acco[f] = __builtin_amdgcn_mfma_f32_16x16x32_bf16(pa, vfrag, acco[f], 0, 0, 0);
        }
    }

    float* ob = out + ((size_t)b * SEQ + wq) * HDIM;
#pragma unroll
    for (int f = 0; f < 8; ++f) {
#pragma unroll
        for (int r = 0; r < 4; ++r) {
            ob[(size_t)(lh * 4 + r) * HDIM + f * 16 + lr] = acco[f][r] / l_r[r];
        }
    }
}

// ---------------------------------------------------------------------------
extern "C" void kernel_launch(void* const* d_in, const int* in_sizes, int n_in,
                              void* d_out, int out_size, void* d_ws, size_t ws_size,
                              hipStream_t stream)
{
    const float* x  = (const float*)d_in[0];
    const float* Wq = (const float*)d_in[1];
    const float* Wk = (const float*)d_in[2];
    const float* Wv = (const float*)d_in[3];
    float* out = (float*)d_out;

    // workspace layout (bf16 elements)
    unsigned short* xbf = (unsigned short*)d_ws;                 // 16384*1024
    unsigned short* wbf = xbf + (size_t)MROWS * DMODEL;          // 384*1024
    unsigned short* qo  = wbf + (size_t)384 * DMODEL;            // 16384*128
    unsigned short* ko  = qo  + (size_t)MROWS * HDIM;            // 16384*128
    unsigned short* vt  = ko  + (size_t)MROWS * HDIM;            // 4*128*4096
    // total: ~44.8 MB

    const float qscale = 0.08838834764831845f;   // 1/sqrt(128)

    const int n8x = MROWS * DMODEL / 8;
    cvt_bf16_kernel<<<(n8x + 255) / 256, 256, 0, stream>>>(x, xbf, n8x, 1.0f);
    const int n8w = HDIM * DMODEL / 8;
    cvt_bf16_kernel<<<(n8w + 255) / 256, 256, 0, stream>>>(Wq, wbf, n8w, qscale);
    cvt_bf16_kernel<<<(n8w + 255) / 256, 256, 0, stream>>>(Wk, wbf + (size_t)HDIM * DMODEL, n8w, 1.0f);
    cvt_bf16_kernel<<<(n8w + 255) / 256, 256, 0, stream>>>(Wv, wbf + (size_t)2 * HDIM * DMODEL, n8w, 1.0f);

    qkv_kernel<<<MROWS / 16, 256, 0, stream>>>(xbf, wbf, qo, ko, vt);

    attn_kernel<<<BATCH * (SEQ / 16), 64, 0, stream>>>(qo, ko, vt, out);
}

// Round 2
// 265.321 us; speedup vs baseline: 1.1448x; 1.1448x over previous
//
#include <hip/hip_runtime.h>
#include <hip/hip_bf16.h>

#define BATCH  4
#define SEQ    4096
#define DMODEL 1024
#define HDIM   128
#define MROWS  (BATCH * SEQ)   // 16384
#define NT     (SEQ / 16)      // 256 q-tiles per batch
#define TILES  (BATCH * NT)    // 1024
#define NS     4               // KV splits per q-tile

typedef __attribute__((ext_vector_type(8))) short short8;
typedef __attribute__((ext_vector_type(4))) float floatx4;

static __device__ __forceinline__ short f2bf(float f) {
    __hip_bfloat16 h = __float2bfloat16(f);
    union { __hip_bfloat16 h; short s; } u; u.h = h;
    return u.s;
}

// ---------------------------------------------------------------------------
// W = [Wq;Wk;Wv] fp32 -> bf16, Wq pre-scaled by 1/sqrt(H). One launch.
// ---------------------------------------------------------------------------
__global__ __launch_bounds__(256) void cvt_w_kernel(
    const float* __restrict__ Wq, const float* __restrict__ Wk,
    const float* __restrict__ Wv, unsigned short* __restrict__ wbf)
{
    const int n8w = HDIM * DMODEL / 8;                // 16384
    int i = blockIdx.x * 256 + threadIdx.x;           // 0 .. 3*n8w-1
    if (i >= 3 * n8w) return;
    const int which = i / n8w;
    const int j = i - which * n8w;
    const float* src = (which == 0) ? Wq : (which == 1) ? Wk : Wv;
    const float scale = (which == 0) ? 0.08838834764831845f : 1.0f;
    const float4* s4 = reinterpret_cast<const float4*>(src);
    float4 a = s4[2 * j];
    float4 b = s4[2 * j + 1];
    short8 o;
    o[0] = f2bf(a.x * scale); o[1] = f2bf(a.y * scale);
    o[2] = f2bf(a.z * scale); o[3] = f2bf(a.w * scale);
    o[4] = f2bf(b.x * scale); o[5] = f2bf(b.y * scale);
    o[6] = f2bf(b.z * scale); o[7] = f2bf(b.w * scale);
    reinterpret_cast<short8*>(wbf)[i] = o;
}

// ---------------------------------------------------------------------------
// QKV projection: y = x @ W^T, x read as fp32 and converted in-register.
// One block = 16 rows of x, 4 waves x 6 col-tiles of 16.
// q,k row-major [MROWS][128] bf16; v transposed [B][128][SEQ].
// MFMA 16x16x32 bf16: A: lane l holds A[l&15][(l>>4)*8+j];
// B: lane l holds B[(l>>4)*8+j][l&15]; C/D: col=l&15, row=(l>>4)*4+reg.
// ---------------------------------------------------------------------------
__global__ __launch_bounds__(256) void qkv_kernel(
    const float* __restrict__ x,             // [MROWS][DMODEL] fp32
    const unsigned short* __restrict__ wbf,  // [384][DMODEL] bf16
    unsigned short* __restrict__ qo,         // [MROWS][HDIM]
    unsigned short* __restrict__ ko,         // [MROWS][HDIM]
    unsigned short* __restrict__ vt)         // [BATCH][HDIM][SEQ]
{
    const int m0   = blockIdx.x * 16;
    const int wave = threadIdx.x >> 6;
    const int lane = threadIdx.x & 63;
    const int lr   = lane & 15;
    const int lh   = lane >> 4;

    floatx4 acc[6];
#pragma unroll
    for (int t = 0; t < 6; ++t) acc[t] = (floatx4){0.f, 0.f, 0.f, 0.f};

    const int cbase = wave * 96;
    const float* xrow = x + (size_t)(m0 + lr) * DMODEL + lh * 8;

    for (int k0 = 0; k0 < DMODEL; k0 += 32) {
        float4 a = *reinterpret_cast<const float4*>(xrow + k0);
        float4 c = *reinterpret_cast<const float4*>(xrow + k0 + 4);
        short8 afrag;
        afrag[0] = f2bf(a.x); afrag[1] = f2bf(a.y);
        afrag[2] = f2bf(a.z); afrag[3] = f2bf(a.w);
        afrag[4] = f2bf(c.x); afrag[5] = f2bf(c.y);
        afrag[6] = f2bf(c.z); afrag[7] = f2bf(c.w);
#pragma unroll
        for (int t = 0; t < 6; ++t) {
            const unsigned short* wrow =
                wbf + (size_t)(cbase + t * 16 + lr) * DMODEL + k0 + lh * 8;
            short8 bfrag = *reinterpret_cast<const short8*>(wrow);
            acc[t] = __builtin_amdgcn_mfma_f32_16x16x32_bf16(afrag, bfrag, acc[t], 0, 0, 0);
        }
    }

#pragma unroll
    for (int t = 0; t < 6; ++t) {
        const int c = cbase + t * 16 + lr;
#pragma unroll
        for (int r = 0; r < 4; ++r) {
            const int gm = m0 + lh * 4 + r;
            const unsigned short v = (unsigned short)f2bf(acc[t][r]);
            if (c < HDIM) {
                qo[(size_t)gm * HDIM + c] = v;
            } else if (c < 2 * HDIM) {
                ko[(size_t)gm * HDIM + (c - HDIM)] = v;
            } else {
                const int b = gm >> 12;          // / SEQ
                const int s = gm & (SEQ - 1);    // % SEQ
                vt[((size_t)b * HDIM + (c - 2 * HDIM)) * SEQ + s] = v;
            }
        }
    }
}

// ---------------------------------------------------------------------------
// Causal flash attention with split-KV. 1 wave per block, 16 q-rows per wave,
// split s of NS handles KV range [s*chunk, min((s+1)*chunk, nkv)).
// Writes UNNORMALIZED partials: pacc [NS][TILES][16][128] f32, pm/pl
// [NS][TILES][16]. Masked scores -> p=0 via explicit select (a split can be
// fully masked for some rows).
// ---------------------------------------------------------------------------
__global__ __launch_bounds__(64) void attn_kernel(
    const unsigned short* __restrict__ qo,
    const unsigned short* __restrict__ ko,
    const unsigned short* __restrict__ vt,
    float* __restrict__ pacc,
    float* __restrict__ pm,
    float* __restrict__ pl)
{
    __shared__ __align__(16) unsigned short p_lds[16][40];  // +8 pad

    const int bid  = blockIdx.x;
    const int tord = bid >> 4;                 // BATCH*NS = 16
    const int rem  = bid & 15;
    const int b    = rem >> 2;
    const int s    = rem & 3;
    const int qt   = (NT - 1) - tord;          // longest first
    const int wq   = qt * 16;
    const int tid  = b * NT + qt;
    const int lane = threadIdx.x & 63;
    const int lr   = lane & 15;
    const int lh   = lane >> 4;

    const int nkv   = wq + 16;
    const int chunk = ((nkv + NS * 32 - 1) / (NS * 32)) * 32;
    const int lo    = s * chunk;
    const int hi    = (lo + chunk < nkv) ? lo + chunk : nkv;

    const size_t pbase = (size_t)(s * TILES + tid) * 16;

    if (lo >= hi) {
        if (lr == 0) {
#pragma unroll
            for (int r = 0; r < 4; ++r) {
                pm[pbase + lh * 4 + r] = -3.0e38f;
                pl[pbase + lh * 4 + r] = 0.f;
            }
        }
        return;
    }

    const unsigned short* qb = qo + ((size_t)b * SEQ + wq) * HDIM;
    const unsigned short* kb = ko + (size_t)b * SEQ * HDIM;
    const unsigned short* vb = vt + (size_t)b * HDIM * SEQ;

    short8 qa[4];
#pragma unroll
    for (int f = 0; f < 4; ++f)
        qa[f] = *reinterpret_cast<const short8*>(qb + (size_t)lr * HDIM + f * 32 + lh * 8);

    floatx4 acco[8];
#pragma unroll
    for (int f = 0; f < 8; ++f) acco[f] = (floatx4){0.f, 0.f, 0.f, 0.f};
    float m_r[4], l_r[4];
#pragma unroll
    for (int r = 0; r < 4; ++r) { m_r[r] = -3.0e38f; l_r[r] = 0.f; }

    for (int kv0 = lo; kv0 < hi; kv0 += 32) {
        // ---- scores: two 16x16 tiles over kv ----
        floatx4 s0 = (floatx4){0.f, 0.f, 0.f, 0.f};
        floatx4 s1 = (floatx4){0.f, 0.f, 0.f, 0.f};
#pragma unroll
        for (int f = 0; f < 4; ++f) {
            short8 b0 = *reinterpret_cast<const short8*>(
                kb + (size_t)(kv0 + lr) * HDIM + f * 32 + lh * 8);
            short8 b1 = *reinterpret_cast<const short8*>(
                kb + (size_t)(kv0 + 16 + lr) * HDIM + f * 32 + lh * 8);
            s0 = __builtin_amdgcn_mfma_f32_16x16x32_bf16(qa[f], b0, s0, 0, 0, 0);
            s1 = __builtin_amdgcn_mfma_f32_16x16x32_bf16(qa[f], b1, s1, 0, 0, 0);
        }
        // ---- causal mask (only diagonal-crossing tiles) ----
        if (kv0 + 31 > wq) {
#pragma unroll
            for (int r = 0; r < 4; ++r) {
                const int qi = wq + lh * 4 + r;
                if (kv0 + lr      > qi) s0[r] = -3.0e38f;
                if (kv0 + 16 + lr > qi) s1[r] = -3.0e38f;
            }
        }
        // ---- online softmax; masked entries contribute exactly 0 ----
#pragma unroll
        for (int r = 0; r < 4; ++r) {
            float t = fmaxf(s0[r], s1[r]);
            t = fmaxf(t, __shfl_xor(t, 1));
            t = fmaxf(t, __shfl_xor(t, 2));
            t = fmaxf(t, __shfl_xor(t, 4));
            t = fmaxf(t, __shfl_xor(t, 8));
            const float mn  = fmaxf(m_r[r], t);
            const float fac = __expf(m_r[r] - mn);
            m_r[r] = mn;
            const float p0 = (s0[r] <= -1.0e38f) ? 0.f : __expf(s0[r] - mn);
            const float p1 = (s1[r] <= -1.0e38f) ? 0.f : __expf(s1[r] - mn);
            p_lds[lh * 4 + r][lr]      = (unsigned short)f2bf(p0);
            p_lds[lh * 4 + r][16 + lr] = (unsigned short)f2bf(p1);
            float ps = p0 + p1;
            ps += __shfl_xor(ps, 1);
            ps += __shfl_xor(ps, 2);
            ps += __shfl_xor(ps, 4);
            ps += __shfl_xor(ps, 8);
            l_r[r] = l_r[r] * fac + ps;
#pragma unroll
            for (int f = 0; f < 8; ++f) acco[f][r] *= fac;
        }
        // ---- PV ----
        short8 pa = *reinterpret_cast<const short8*>(&p_lds[lr][lh * 8]);
#pragma unroll
        for (int f = 0; f < 8; ++f) {
            short8 vfrag = *reinterpret_cast<const short8*>(
                vb + (size_t)(f * 16 + lr) * SEQ + kv0 + lh * 8);
            acco[f] = __builtin_amdgcn_mfma_f32_16x16x32_bf16(pa, vfrag, acco[f], 0, 0, 0);
        }
    }

    // ---- write unnormalized partials ----
    float* pa_out = pacc + pbase * 128;
#pragma unroll
    for (int f = 0; f < 8; ++f)
#pragma unroll
        for (int r = 0; r < 4; ++r)
            pa_out[(size_t)(lh * 4 + r) * 128 + f * 16 + lr] = acco[f][r];
    if (lr == 0) {
#pragma unroll
        for (int r = 0; r < 4; ++r) {
            pm[pbase + lh * 4 + r] = m_r[r];
            pl[pbase + lh * 4 + r] = l_r[r];
        }
    }
}

// ---------------------------------------------------------------------------
// Combine NS partials per q-row: out = sum_s exp(m_s-M) acc_s / sum_s exp(m_s-M) l_s
// One thread per float4 of output.
// ---------------------------------------------------------------------------
__global__ __launch_bounds__(256) void combine_kernel(
    const float* __restrict__ pacc, const float* __restrict__ pm,
    const float* __restrict__ pl, float* __restrict__ out)
{
    const int t   = blockIdx.x * 256 + threadIdx.x;
    const int row = t >> 5;            // 32 float4 per 128-col row
    const int c4  = (t & 31) * 4;
    const int tid = row >> 4;
    const int r16 = row & 15;

    float m[NS];
    float M = -3.0e38f;
#pragma unroll
    for (int s = 0; s < NS; ++s) {
        m[s] = pm[(size_t)(s * TILES + tid) * 16 + r16];
        M = fmaxf(M, m[s]);
    }
    float denom = 0.f;
    float4 acc = make_float4(0.f, 0.f, 0.f, 0.f);
#pragma unroll
    for (int s = 0; s < NS; ++s) {
        const float w = __expf(m[s] - M);
        denom += w * pl[(size_t)(s * TILES + tid) * 16 + r16];
        const float4 a = *reinterpret_cast<const float4*>(
            pacc + ((size_t)(s * TILES + tid) * 16 + r16) * 128 + c4);
        acc.x += w * a.x; acc.y += w * a.y;
        acc.z += w * a.z; acc.w += w * a.w;
    }
    const float inv = 1.f / denom;
    float4 o = make_float4(acc.x * inv, acc.y * inv, acc.z * inv, acc.w * inv);
    *reinterpret_cast<float4*>(out + (size_t)row * 128 + c4) = o;
}

// ---------------------------------------------------------------------------
extern "C" void kernel_launch(void* const* d_in, const int* in_sizes, int n_in,
                              void* d_out, int out_size, void* d_ws, size_t ws_size,
                              hipStream_t stream)
{
    const float* x  = (const float*)d_in[0];
    const float* Wq = (const float*)d_in[1];
    const float* Wk = (const float*)d_in[2];
    const float* Wv = (const float*)d_in[3];
    float* out = (float*)d_out;

    // workspace layout
    unsigned short* wbf = (unsigned short*)d_ws;                 // 384*1024 bf16
    unsigned short* qo  = wbf + (size_t)384 * DMODEL;            // 16384*128
    unsigned short* ko  = qo  + (size_t)MROWS * HDIM;
    unsigned short* vt  = ko  + (size_t)MROWS * HDIM;            // 4*128*4096
    float* pacc = (float*)(vt + (size_t)BATCH * HDIM * SEQ);     // NS*1024*16*128 f32 = 32MB
    float* pm   = pacc + (size_t)NS * TILES * 16 * 128;          // NS*1024*16
    float* pl   = pm   + (size_t)NS * TILES * 16;
    // total ~45.3 MB

    const int n8w3 = 3 * HDIM * DMODEL / 8;
    cvt_w_kernel<<<(n8w3 + 255) / 256, 256, 0, stream>>>(Wq, Wk, Wv, wbf);

    qkv_kernel<<<MROWS / 16, 256, 0, stream>>>(x, wbf, qo, ko, vt);

    attn_kernel<<<TILES * NS, 64, 0, stream>>>(qo, ko, vt, pacc, pm, pl);

    combine_kernel<<<MROWS * HDIM / 4 / 256, 256, 0, stream>>>(pacc, pm, pl, out);
}

// Round 3
// 176.751 us; speedup vs baseline: 1.7185x; 1.5011x over previous
//
#include <hip/hip_runtime.h>
#include <hip/hip_bf16.h>

#define BATCH  4
#define SEQ    4096
#define DMODEL 1024
#define HDIM   128
#define MROWS  (BATCH * SEQ)   // 16384
#define T32PB  (SEQ / 32)      // 128 q-tiles (32 rows) per batch
#define T32    (BATCH * T32PB) // 512
#define NS     4               // KV splits per q-tile

typedef __attribute__((ext_vector_type(8)))  short short8;
typedef __attribute__((ext_vector_type(4)))  float floatx4;
typedef __attribute__((ext_vector_type(16))) float floatx16;
typedef unsigned int u32;

static __device__ __forceinline__ short f2bf(float f) {
    __hip_bfloat16 h = __float2bfloat16(f);
    union { __hip_bfloat16 h; short s; } u; u.h = h;
    return u.s;
}

static __device__ __forceinline__ short8 ld8(const unsigned short* p) {
    return *reinterpret_cast<const short8*>(p);
}

// pack two f32 -> one u32 of two bf16 (lo = a, hi = b)
static __device__ __forceinline__ u32 cvtpk_bf16(float a, float b) {
    u32 r;
    asm("v_cvt_pk_bf16_f32 %0, %1, %2" : "=v"(r) : "v"(a), "v"(b));
    return r;
}

// a' = {lanes<32: a ; lanes>=32: b from partner(lane-32)}
// b' = {lanes<32: a from partner(lane+32) ; lanes>=32: b}
static __device__ __forceinline__ void swap_halves(u32& a, u32& b) {
#if __has_builtin(__builtin_amdgcn_permlane32_swap)
    typedef __attribute__((ext_vector_type(2))) int int2v;
    int2v r = __builtin_amdgcn_permlane32_swap((int)a, (int)b, false, false);
    a = (u32)r[0]; b = (u32)r[1];
#else
    u32 ap = (u32)__shfl_xor((int)a, 32);
    u32 bp = (u32)__shfl_xor((int)b, 32);
    const bool hih = (threadIdx.x & 32) != 0;
    u32 na = hih ? bp : a;
    u32 nb = hih ? b : ap;
    a = na; b = nb;
#endif
}

// ---------------------------------------------------------------------------
// W = [Wq;Wk;Wv] fp32 -> bf16, Wq pre-scaled by 1/sqrt(H). One launch.
// ---------------------------------------------------------------------------
__global__ __launch_bounds__(256) void cvt_w_kernel(
    const float* __restrict__ Wq, const float* __restrict__ Wk,
    const float* __restrict__ Wv, unsigned short* __restrict__ wbf)
{
    const int n8w = HDIM * DMODEL / 8;                // 16384
    int i = blockIdx.x * 256 + threadIdx.x;
    if (i >= 3 * n8w) return;
    const int which = i / n8w;
    const int j = i - which * n8w;
    const float* src = (which == 0) ? Wq : (which == 1) ? Wk : Wv;
    const float scale = (which == 0) ? 0.08838834764831845f : 1.0f;
    const float4* s4 = reinterpret_cast<const float4*>(src);
    float4 a = s4[2 * j];
    float4 b = s4[2 * j + 1];
    short8 o;
    o[0] = f2bf(a.x * scale); o[1] = f2bf(a.y * scale);
    o[2] = f2bf(a.z * scale); o[3] = f2bf(a.w * scale);
    o[4] = f2bf(b.x * scale); o[5] = f2bf(b.y * scale);
    o[6] = f2bf(b.z * scale); o[7] = f2bf(b.w * scale);
    reinterpret_cast<short8*>(wbf)[i] = o;
}

// ---------------------------------------------------------------------------
// QKV projection: y = x @ W^T. One block = 32 rows, 4 waves x (2 row-tiles x
// 6 col-tiles). q,k row-major [MROWS][128] bf16; v transposed [B][128][SEQ].
// ---------------------------------------------------------------------------
__global__ __launch_bounds__(256) void qkv_kernel(
    const float* __restrict__ x,
    const unsigned short* __restrict__ wbf,
    unsigned short* __restrict__ qo,
    unsigned short* __restrict__ ko,
    unsigned short* __restrict__ vt)
{
    const int m0   = blockIdx.x * 32;
    const int wave = threadIdx.x >> 6;
    const int lane = threadIdx.x & 63;
    const int lr   = lane & 15;
    const int lh   = lane >> 4;

    floatx4 acc[2][6];
#pragma unroll
    for (int rt = 0; rt < 2; ++rt)
#pragma unroll
        for (int t = 0; t < 6; ++t) acc[rt][t] = (floatx4){0.f, 0.f, 0.f, 0.f};

    const int cbase = wave * 96;
    const float* xr0 = x + (size_t)(m0 + lr) * DMODEL + lh * 8;
    const float* xr1 = xr0 + (size_t)16 * DMODEL;

    for (int k0 = 0; k0 < DMODEL; k0 += 32) {
        float4 a0 = *reinterpret_cast<const float4*>(xr0 + k0);
        float4 a1 = *reinterpret_cast<const float4*>(xr0 + k0 + 4);
        float4 b0 = *reinterpret_cast<const float4*>(xr1 + k0);
        float4 b1 = *reinterpret_cast<const float4*>(xr1 + k0 + 4);
        short8 af, bf;
        af[0] = f2bf(a0.x); af[1] = f2bf(a0.y); af[2] = f2bf(a0.z); af[3] = f2bf(a0.w);
        af[4] = f2bf(a1.x); af[5] = f2bf(a1.y); af[6] = f2bf(a1.z); af[7] = f2bf(a1.w);
        bf[0] = f2bf(b0.x); bf[1] = f2bf(b0.y); bf[2] = f2bf(b0.z); bf[3] = f2bf(b0.w);
        bf[4] = f2bf(b1.x); bf[5] = f2bf(b1.y); bf[6] = f2bf(b1.z); bf[7] = f2bf(b1.w);
#pragma unroll
        for (int t = 0; t < 6; ++t) {
            const unsigned short* wrow =
                wbf + (size_t)(cbase + t * 16 + lr) * DMODEL + k0 + lh * 8;
            short8 wf = ld8(wrow);
            acc[0][t] = __builtin_amdgcn_mfma_f32_16x16x32_bf16(af, wf, acc[0][t], 0, 0, 0);
            acc[1][t] = __builtin_amdgcn_mfma_f32_16x16x32_bf16(bf, wf, acc[1][t], 0, 0, 0);
        }
    }

#pragma unroll
    for (int rt = 0; rt < 2; ++rt) {
#pragma unroll
        for (int t = 0; t < 6; ++t) {
            const int c = cbase + t * 16 + lr;
#pragma unroll
            for (int r = 0; r < 4; ++r) {
                const int gm = m0 + rt * 16 + lh * 4 + r;
                const unsigned short v = (unsigned short)f2bf(acc[rt][t][r]);
                if (c < HDIM) {
                    qo[(size_t)gm * HDIM + c] = v;
                } else if (c < 2 * HDIM) {
                    ko[(size_t)gm * HDIM + (c - HDIM)] = v;
                } else {
                    const int b = gm >> 12;
                    const int s = gm & (SEQ - 1);
                    vt[((size_t)b * HDIM + (c - 2 * HDIM)) * SEQ + s] = v;
                }
            }
        }
    }
}

// ---------------------------------------------------------------------------
// Causal flash attention, swapped QK^T, 32x32x16 MFMA, in-register softmax.
// 1 wave per block, 32 q-rows per wave, KVBLK=32, split-KV NS=4.
// Each lane owns one q-row (q = q0 + (lane&31)); its 32 scores per KV tile
// live in sc[0..15] at kv = kv0 + (r&3)+8*(r>>2)+4*(lane>>5).
// O accumulated transposed; partials written as pacc_t[split][t32][128d][32q].
// ---------------------------------------------------------------------------
__global__ __launch_bounds__(64) void attn_kernel(
    const unsigned short* __restrict__ qo,
    const unsigned short* __restrict__ ko,
    const unsigned short* __restrict__ vt,
    float* __restrict__ pacc,
    float* __restrict__ pm,
    float* __restrict__ pl)
{
    const int bid  = blockIdx.x;
    const int tord = bid >> 4;
    const int b    = (bid >> 2) & 3;
    const int s    = bid & 3;
    const int t32b = (T32PB - 1) - tord;      // longest first
    const int q0   = t32b * 32;
    const int t32  = b * T32PB + t32b;
    const int lane = threadIdx.x & 63;
    const int l31  = lane & 31;
    const int hih  = lane >> 5;

    const int nkv   = q0 + 32;
    const int chunk = ((nkv + NS * 32 - 1) / (NS * 32)) * 32;
    const int lo    = s * chunk;
    const int hikv  = (lo + chunk < nkv) ? lo + chunk : nkv;
    const size_t mlbase = (size_t)(s * T32 + t32) * 32;

    if (lo >= hikv) {
        if (lane < 32) { pm[mlbase + l31] = -3.0e38f; pl[mlbase + l31] = 0.f; }
        return;
    }

    // Q fragments: lane holds Q[q0+l31][ks*16 + hih*8 + j]
    const unsigned short* qb = qo + ((size_t)b * SEQ + q0 + l31) * HDIM + hih * 8;
    short8 qa[8];
#pragma unroll
    for (int ks = 0; ks < 8; ++ks) qa[ks] = ld8(qb + ks * 16);

    const unsigned short* kb = ko + ((size_t)b * SEQ + l31) * HDIM + hih * 8;
    const unsigned short* vb = vt + ((size_t)b * HDIM + l31) * SEQ + hih * 8;

    floatx16 acco[4];
#pragma unroll
    for (int db = 0; db < 4; ++db)
#pragma unroll
        for (int i = 0; i < 16; ++i) acco[db][i] = 0.f;
    float m_r = -3.0e38f, l_r = 0.f;

    for (int kv0 = lo; kv0 < hikv; kv0 += 32) {
        // ---- scores S^T[kv][q] = mfma(K, Q) ----
        floatx16 sc;
#pragma unroll
        for (int i = 0; i < 16; ++i) sc[i] = 0.f;
#pragma unroll
        for (int ks = 0; ks < 8; ++ks) {
            short8 kf = ld8(kb + (size_t)kv0 * HDIM + ks * 16);
            sc = __builtin_amdgcn_mfma_f32_32x32x16_bf16(kf, qa[ks], sc, 0, 0, 0);
        }
        // ---- causal mask: only the diagonal tile ----
        if (kv0 == q0) {
#pragma unroll
            for (int r = 0; r < 16; ++r) {
                const int kvloc = (r & 3) + 8 * (r >> 2) + 4 * hih;
                if (kvloc > l31) sc[r] = -3.0e38f;
            }
        }
        // ---- lane-local max (tree) + cross-half ----
        float t8[8];
#pragma unroll
        for (int i = 0; i < 8; ++i) t8[i] = fmaxf(sc[i], sc[i + 8]);
        float t4a = fmaxf(t8[0], t8[4]), t4b = fmaxf(t8[1], t8[5]);
        float t4c = fmaxf(t8[2], t8[6]), t4d = fmaxf(t8[3], t8[7]);
        float pmax = fmaxf(fmaxf(t4a, t4b), fmaxf(t4c, t4d));
        pmax = fmaxf(pmax, __shfl_xor(pmax, 32));
        // ---- deferred rescale (T13, THR=8) ----
        if (__any(pmax > m_r + 8.f)) {
            const float mn  = fmaxf(m_r, pmax);
            const float fac = __expf(m_r - mn);
            m_r = mn; l_r *= fac;
#pragma unroll
            for (int db = 0; db < 4; ++db)
#pragma unroll
                for (int i = 0; i < 16; ++i) acco[db][i] *= fac;
        }
        // ---- p = exp(s - m), lane-local sum ----
        float p[16];
#pragma unroll
        for (int r = 0; r < 16; ++r) p[r] = __expf(sc[r] - m_r);
        float s8[8];
#pragma unroll
        for (int i = 0; i < 8; ++i) s8[i] = p[i] + p[i + 8];
        float s4a = s8[0] + s8[4], s4b = s8[1] + s8[5];
        float s4c = s8[2] + s8[6], s4d = s8[3] + s8[7];
        float ps = (s4a + s4b) + (s4c + s4d);
        ps += __shfl_xor(ps, 32);
        l_r += ps;
        // ---- pack P^T B-fragments (T12: cvt_pk + permlane32_swap) ----
        u32 pk0 = cvtpk_bf16(p[0], p[1]),   pk2 = cvtpk_bf16(p[4], p[5]);
        swap_halves(pk0, pk2);
        u32 pk1 = cvtpk_bf16(p[2], p[3]),   pk3 = cvtpk_bf16(p[6], p[7]);
        swap_halves(pk1, pk3);
        u32 pk4 = cvtpk_bf16(p[8], p[9]),   pk6 = cvtpk_bf16(p[12], p[13]);
        swap_halves(pk4, pk6);
        u32 pk5 = cvtpk_bf16(p[10], p[11]), pk7 = cvtpk_bf16(p[14], p[15]);
        swap_halves(pk5, pk7);
        union { u32 u[4]; short8 s8v; } ua, ub;
        ua.u[0] = pk0; ua.u[1] = pk1; ua.u[2] = pk2; ua.u[3] = pk3;
        ub.u[0] = pk4; ub.u[1] = pk5; ub.u[2] = pk6; ub.u[3] = pk7;
        const short8 pa0 = ua.s8v, pa1 = ub.s8v;
        // ---- PV: O^T[d][q] += V^T x P^T ----
#pragma unroll
        for (int db = 0; db < 4; ++db) {
            short8 vf0 = ld8(vb + (size_t)(db * 32) * SEQ + kv0);
            acco[db] = __builtin_amdgcn_mfma_f32_32x32x16_bf16(vf0, pa0, acco[db], 0, 0, 0);
            short8 vf1 = ld8(vb + (size_t)(db * 32) * SEQ + kv0 + 16);
            acco[db] = __builtin_amdgcn_mfma_f32_32x32x16_bf16(vf1, pa1, acco[db], 0, 0, 0);
        }
    }

    // ---- write partials (transposed, coalesced over q) ----
    float* pt = pacc + (size_t)(s * T32 + t32) * 128 * 32;
#pragma unroll
    for (int db = 0; db < 4; ++db)
#pragma unroll
        for (int r = 0; r < 16; ++r) {
            const int dloc = db * 32 + (r & 3) + 8 * (r >> 2) + 4 * hih;
            pt[(size_t)dloc * 32 + l31] = acco[db][r];
        }
    if (lane < 32) { pm[mlbase + l31] = m_r; pl[mlbase + l31] = l_r; }
}

// ---------------------------------------------------------------------------
// Combine NS partials per 32-row tile; LDS transpose for coalesced output.
// ---------------------------------------------------------------------------
__global__ __launch_bounds__(256) void combine_kernel(
    const float* __restrict__ pacc, const float* __restrict__ pm,
    const float* __restrict__ pl, float* __restrict__ out)
{
    __shared__ float wlds[NS][32];
    __shared__ float tlds[128][33];
    const int t32 = blockIdx.x;
    const int tid = threadIdx.x;

    if (tid < 32) {
        const int q = tid;
        float ms[NS], ls[NS];
        float M = -3.0e38f;
#pragma unroll
        for (int s = 0; s < NS; ++s) {
            ms[s] = pm[(size_t)(s * T32 + t32) * 32 + q];
            ls[s] = pl[(size_t)(s * T32 + t32) * 32 + q];
            M = fmaxf(M, ms[s]);
        }
        float w[NS], den = 0.f;
#pragma unroll
        for (int s = 0; s < NS; ++s) { w[s] = __expf(ms[s] - M); den += w[s] * ls[s]; }
        const float inv = 1.f / den;
#pragma unroll
        for (int s = 0; s < NS; ++s) wlds[s][q] = w[s] * inv;
    }
    __syncthreads();

#pragma unroll
    for (int rep = 0; rep < 16; ++rep) {
        const int flat = rep * 256 + tid;
        const int d = flat >> 5, q = flat & 31;
        float acc = 0.f;
#pragma unroll
        for (int s = 0; s < NS; ++s)
            acc += wlds[s][q] * pacc[((size_t)(s * T32 + t32) * 128 + d) * 32 + q];
        tlds[d][q] = acc;
    }
    __syncthreads();

    const size_t row0 = (size_t)t32 * 32;
#pragma unroll
    for (int rep = 0; rep < 16; ++rep) {
        const int flat = rep * 256 + tid;
        const int q = flat >> 7, d = flat & 127;
        out[(row0 + q) * 128 + d] = tlds[d][q];
    }
}

// ---------------------------------------------------------------------------
extern "C" void kernel_launch(void* const* d_in, const int* in_sizes, int n_in,
                              void* d_out, int out_size, void* d_ws, size_t ws_size,
                              hipStream_t stream)
{
    const float* x  = (const float*)d_in[0];
    const float* Wq = (const float*)d_in[1];
    const float* Wk = (const float*)d_in[2];
    const float* Wv = (const float*)d_in[3];
    float* out = (float*)d_out;

    unsigned short* wbf = (unsigned short*)d_ws;                 // 384*1024 bf16
    unsigned short* qo  = wbf + (size_t)384 * DMODEL;            // 16384*128
    unsigned short* ko  = qo  + (size_t)MROWS * HDIM;
    unsigned short* vt  = ko  + (size_t)MROWS * HDIM;            // 4*128*4096
    float* pacc = (float*)(vt + (size_t)BATCH * HDIM * SEQ);     // NS*512*128*32 f32
    float* pm   = pacc + (size_t)NS * T32 * 128 * 32;
    float* pl   = pm   + (size_t)NS * T32 * 32;
    // total ~46.9 MB (same footprint as round 2)

    const int n8w3 = 3 * HDIM * DMODEL / 8;
    cvt_w_kernel<<<(n8w3 + 255) / 256, 256, 0, stream>>>(Wq, Wk, Wv, wbf);

    qkv_kernel<<<MROWS / 32, 256, 0, stream>>>(x, wbf, qo, ko, vt);

    attn_kernel<<<T32 * NS, 64, 0, stream>>>(qo, ko, vt, pacc, pm, pl);

    combine_kernel<<<T32, 256, 0, stream>>>(pacc, pm, pl, out);
}

// Round 5
// 161.139 us; speedup vs baseline: 1.8850x; 1.0969x over previous
//
#include <hip/hip_runtime.h>
#include <hip/hip_bf16.h>

#define BATCH  4
#define SEQ    4096
#define DMODEL 1024
#define HDIM   128
#define MROWS  (BATCH * SEQ)   // 16384
#define T32PB  (SEQ / 32)      // 128 q-tiles (32 rows) per batch
#define T32    (BATCH * T32PB) // 512
#define NS     4               // KV splits per q-tile

// qkv GEMM tile
#define BM 128
#define BN 96
#define BK 64
#define PK 72                  // padded LDS row (shorts): +16B -> 2-way (free)
#define KT (DMODEL / BK)       // 16

typedef __attribute__((ext_vector_type(8)))  short short8;
typedef __attribute__((ext_vector_type(4)))  float floatx4;
typedef __attribute__((ext_vector_type(16))) float floatx16;
typedef unsigned int u32;

static __device__ __forceinline__ short f2bf(float f) {
    __hip_bfloat16 h = __float2bfloat16(f);
    union { __hip_bfloat16 h; short s; } u; u.h = h;
    return u.s;
}

static __device__ __forceinline__ short8 ld8(const unsigned short* p) {
    return *reinterpret_cast<const short8*>(p);
}

// pack two f32 -> one u32 of two bf16 (lo = a, hi = b)
static __device__ __forceinline__ u32 cvtpk_bf16(float a, float b) {
    u32 r;
    asm("v_cvt_pk_bf16_f32 %0, %1, %2" : "=v"(r) : "v"(a), "v"(b));
    return r;
}

// a' = {lanes<32: a ; lanes>=32: b from partner(lane-32)}
// b' = {lanes<32: a from partner(lane+32) ; lanes>=32: b}
static __device__ __forceinline__ void swap_halves(u32& a, u32& b) {
#if __has_builtin(__builtin_amdgcn_permlane32_swap)
    typedef __attribute__((ext_vector_type(2))) int int2v;
    int2v r = __builtin_amdgcn_permlane32_swap((int)a, (int)b, false, false);
    a = (u32)r[0]; b = (u32)r[1];
#else
    u32 ap = (u32)__shfl_xor((int)a, 32);
    u32 bp = (u32)__shfl_xor((int)b, 32);
    const bool hih = (threadIdx.x & 32) != 0;
    u32 na = hih ? bp : a;
    u32 nb = hih ? b : ap;
    a = na; b = nb;
#endif
}

// ---------------------------------------------------------------------------
// W = [Wq;Wk;Wv] fp32 -> bf16, Wq pre-scaled by 1/sqrt(H). One launch.
// ---------------------------------------------------------------------------
__global__ __launch_bounds__(256) void cvt_w_kernel(
    const float* __restrict__ Wq, const float* __restrict__ Wk,
    const float* __restrict__ Wv, unsigned short* __restrict__ wbf)
{
    const int n8w = HDIM * DMODEL / 8;                // 16384
    int i = blockIdx.x * 256 + threadIdx.x;
    if (i >= 3 * n8w) return;
    const int which = i / n8w;
    const int j = i - which * n8w;
    const float* src = (which == 0) ? Wq : (which == 1) ? Wk : Wv;
    const float scale = (which == 0) ? 0.08838834764831845f : 1.0f;
    const float4* s4 = reinterpret_cast<const float4*>(src);
    float4 a = s4[2 * j];
    float4 b = s4[2 * j + 1];
    short8 o;
    o[0] = f2bf(a.x * scale); o[1] = f2bf(a.y * scale);
    o[2] = f2bf(a.z * scale); o[3] = f2bf(a.w * scale);
    o[4] = f2bf(b.x * scale); o[5] = f2bf(b.y * scale);
    o[6] = f2bf(b.z * scale); o[7] = f2bf(b.w * scale);
    reinterpret_cast<short8*>(wbf)[i] = o;
}

// ---------------------------------------------------------------------------
// QKV projection as single-buffered LDS-tiled GEMM (m97-style 2-barrier loop).
// y = x @ W^T.  M=16384, N=384, K=1024. BM=128 x BN=96 x BK=64, 4 waves 2x2,
// each wave 64x48 = 4x3 16x16 fragments, 24 MFMA per K-step.
// Reg-staged loads only; padded LDS rows (PK=72) -> no swizzle needed.
// ---------------------------------------------------------------------------
__global__ __launch_bounds__(256, 2) void qkv_kernel(
    const float* __restrict__ x,             // [MROWS][DMODEL] fp32
    const unsigned short* __restrict__ wbf,  // [384][DMODEL] bf16
    unsigned short* __restrict__ qo,         // [MROWS][HDIM]
    unsigned short* __restrict__ ko,         // [MROWS][HDIM]
    unsigned short* __restrict__ vt)         // [BATCH][HDIM][SEQ]
{
    __shared__ __align__(16) unsigned short A_lds[BM][PK];  // 18 KB
    __shared__ __align__(16) unsigned short B_lds[BN][PK];  // 13.5 KB

    // XCD-chunked swizzle (512 % 8 == 0 -> bijective): the 4 N-blocks of an
    // x row-panel land on the same XCD -> x read once per XCD L2.
    const int raw  = blockIdx.x;
    const int vid  = (raw & 7) * 64 + (raw >> 3);
    const int mblk = vid >> 2;
    const int nblk = vid & 3;
    const int m0   = mblk * BM;
    const int n0   = nblk * BN;

    const int tid  = threadIdx.x;
    const int wv   = tid >> 6;
    const int lane = tid & 63;
    const int lr   = lane & 15;
    const int lh   = lane >> 4;
    const int wm   = wv >> 1;   // 0/1 -> M offset 0/64
    const int wn   = wv & 1;    // 0/1 -> N offset 0/48

    // A staging: thread -> row ar=tid>>1, k-half akh=tid&1 (32 floats each)
    const int ar  = tid >> 1;
    const int akh = tid & 1;

    floatx4 acc[4][3];
#pragma unroll
    for (int mf = 0; mf < 4; ++mf)
#pragma unroll
        for (int nf = 0; nf < 3; ++nf) acc[mf][nf] = (floatx4){0.f, 0.f, 0.f, 0.f};

    for (int kt = 0; kt < KT; ++kt) {
        // ---- stage A: fp32 -> bf16, linear padded rows ----
        const float* a = x + (size_t)(m0 + ar) * DMODEL + kt * BK + akh * 32;
#pragma unroll
        for (int j = 0; j < 4; ++j) {
            float4 f0 = *reinterpret_cast<const float4*>(a + j * 8);
            float4 f1 = *reinterpret_cast<const float4*>(a + j * 8 + 4);
            short8 v;
            v[0] = f2bf(f0.x); v[1] = f2bf(f0.y); v[2] = f2bf(f0.z); v[3] = f2bf(f0.w);
            v[4] = f2bf(f1.x); v[5] = f2bf(f1.y); v[6] = f2bf(f1.z); v[7] = f2bf(f1.w);
            *reinterpret_cast<short8*>(&A_lds[ar][(akh * 4 + j) * 8]) = v;
        }
        // ---- stage B: 96x64 shorts = 768 short8 units, 3 per thread ----
#pragma unroll
        for (int j = 0; j < 3; ++j) {
            const int f   = tid + 256 * j;
            const int row = f >> 3;
            const int u   = f & 7;
            short8 w8 = ld8(wbf + (size_t)(n0 + row) * DMODEL + kt * BK + u * 8);
            *reinterpret_cast<short8*>(&B_lds[row][u * 8]) = w8;
        }
        __syncthreads();
        // ---- compute: 2 k-steps of 32, 12 MFMA each ----
#pragma unroll
        for (int kk = 0; kk < 2; ++kk) {
            const int ub = (kk * 4 + lh) * 8;
            short8 af[4], bfr[3];
#pragma unroll
            for (int mf = 0; mf < 4; ++mf)
                af[mf] = ld8(&A_lds[wm * 64 + mf * 16 + lr][ub]);
#pragma unroll
            for (int nf = 0; nf < 3; ++nf)
                bfr[nf] = ld8(&B_lds[wn * 48 + nf * 16 + lr][ub]);
#pragma unroll
            for (int mf = 0; mf < 4; ++mf)
#pragma unroll
                for (int nf = 0; nf < 3; ++nf)
                    acc[mf][nf] = __builtin_amdgcn_mfma_f32_16x16x32_bf16(
                        af[mf], bfr[nf], acc[mf][nf], 0, 0, 0);
        }
        __syncthreads();
    }

    // ---- epilogue: route to q / k / v^T (round-3 proven mapping) ----
#pragma unroll
    for (int nf = 0; nf < 3; ++nf) {
        const int c = n0 + wn * 48 + nf * 16 + lr;
#pragma unroll
        for (int mf = 0; mf < 4; ++mf) {
#pragma unroll
            for (int r = 0; r < 4; ++r) {
                const int gm = m0 + wm * 64 + mf * 16 + lh * 4 + r;
                const unsigned short vv = (unsigned short)f2bf(acc[mf][nf][r]);
                if (c < HDIM) {
                    qo[(size_t)gm * HDIM + c] = vv;
                } else if (c < 2 * HDIM) {
                    ko[(size_t)gm * HDIM + (c - HDIM)] = vv;
                } else {
                    const int b  = gm >> 12;
                    const int sx = gm & (SEQ - 1);
                    vt[((size_t)b * HDIM + (c - 2 * HDIM)) * SEQ + sx] = vv;
                }
            }
        }
    }
}

// ---------------------------------------------------------------------------
// Causal flash attention, swapped QK^T, 32x32x16 MFMA, in-register softmax.
// 1 wave per block, 32 q-rows per wave, KVBLK=32, split-KV NS=4.
// (byte-identical to the round-3 passing version)
// ---------------------------------------------------------------------------
__global__ __launch_bounds__(64) void attn_kernel(
    const unsigned short* __restrict__ qo,
    const unsigned short* __restrict__ ko,
    const unsigned short* __restrict__ vt,
    float* __restrict__ pacc,
    float* __restrict__ pm,
    float* __restrict__ pl)
{
    const int bid  = blockIdx.x;
    const int tord = bid >> 4;
    const int b    = (bid >> 2) & 3;
    const int s    = bid & 3;
    const int t32b = (T32PB - 1) - tord;      // longest first
    const int q0   = t32b * 32;
    const int t32  = b * T32PB + t32b;
    const int lane = threadIdx.x & 63;
    const int l31  = lane & 31;
    const int hih  = lane >> 5;

    const int nkv   = q0 + 32;
    const int chunk = ((nkv + NS * 32 - 1) / (NS * 32)) * 32;
    const int lo    = s * chunk;
    const int hikv  = (lo + chunk < nkv) ? lo + chunk : nkv;
    const size_t mlbase = (size_t)(s * T32 + t32) * 32;

    if (lo >= hikv) {
        if (lane < 32) { pm[mlbase + l31] = -3.0e38f; pl[mlbase + l31] = 0.f; }
        return;
    }

    // Q fragments: lane holds Q[q0+l31][ks*16 + hih*8 + j]
    const unsigned short* qb = qo + ((size_t)b * SEQ + q0 + l31) * HDIM + hih * 8;
    short8 qa[8];
#pragma unroll
    for (int ks = 0; ks < 8; ++ks) qa[ks] = ld8(qb + ks * 16);

    const unsigned short* kb = ko + ((size_t)b * SEQ + l31) * HDIM + hih * 8;
    const unsigned short* vb = vt + ((size_t)b * HDIM + l31) * SEQ + hih * 8;

    floatx16 acco[4];
#pragma unroll
    for (int db = 0; db < 4; ++db)
#pragma unroll
        for (int i = 0; i < 16; ++i) acco[db][i] = 0.f;
    float m_r = -3.0e38f, l_r = 0.f;

    for (int kv0 = lo; kv0 < hikv; kv0 += 32) {
        // ---- scores S^T[kv][q] = mfma(K, Q) ----
        floatx16 sc;
#pragma unroll
        for (int i = 0; i < 16; ++i) sc[i] = 0.f;
#pragma unroll
        for (int ks = 0; ks < 8; ++ks) {
            short8 kf = ld8(kb + (size_t)kv0 * HDIM + ks * 16);
            sc = __builtin_amdgcn_mfma_f32_32x32x16_bf16(kf, qa[ks], sc, 0, 0, 0);
        }
        // ---- causal mask: only the diagonal tile ----
        if (kv0 == q0) {
#pragma unroll
            for (int r = 0; r < 16; ++r) {
                const int kvloc = (r & 3) + 8 * (r >> 2) + 4 * hih;
                if (kvloc > l31) sc[r] = -3.0e38f;
            }
        }
        // ---- lane-local max (tree) + cross-half ----
        float t8[8];
#pragma unroll
        for (int i = 0; i < 8; ++i) t8[i] = fmaxf(sc[i], sc[i + 8]);
        float t4a = fmaxf(t8[0], t8[4]), t4b = fmaxf(t8[1], t8[5]);
        float t4c = fmaxf(t8[2], t8[6]), t4d = fmaxf(t8[3], t8[7]);
        float pmax = fmaxf(fmaxf(t4a, t4b), fmaxf(t4c, t4d));
        pmax = fmaxf(pmax, __shfl_xor(pmax, 32));
        // ---- deferred rescale (T13, THR=8) ----
        if (__any(pmax > m_r + 8.f)) {
            const float mn  = fmaxf(m_r, pmax);
            const float fac = __expf(m_r - mn);
            m_r = mn; l_r *= fac;
#pragma unroll
            for (int db = 0; db < 4; ++db)
#pragma unroll
                for (int i = 0; i < 16; ++i) acco[db][i] *= fac;
        }
        // ---- p = exp(s - m), lane-local sum ----
        float p[16];
#pragma unroll
        for (int r = 0; r < 16; ++r) p[r] = __expf(sc[r] - m_r);
        float s8[8];
#pragma unroll
        for (int i = 0; i < 8; ++i) s8[i] = p[i] + p[i + 8];
        float s4a = s8[0] + s8[4], s4b = s8[1] + s8[5];
        float s4c = s8[2] + s8[6], s4d = s8[3] + s8[7];
        float ps = (s4a + s4b) + (s4c + s4d);
        ps += __shfl_xor(ps, 32);
        l_r += ps;
        // ---- pack P^T B-fragments (T12: cvt_pk + permlane32_swap) ----
        u32 pk0 = cvtpk_bf16(p[0], p[1]),   pk2 = cvtpk_bf16(p[4], p[5]);
        swap_halves(pk0, pk2);
        u32 pk1 = cvtpk_bf16(p[2], p[3]),   pk3 = cvtpk_bf16(p[6], p[7]);
        swap_halves(pk1, pk3);
        u32 pk4 = cvtpk_bf16(p[8], p[9]),   pk6 = cvtpk_bf16(p[12], p[13]);
        swap_halves(pk4, pk6);
        u32 pk5 = cvtpk_bf16(p[10], p[11]), pk7 = cvtpk_bf16(p[14], p[15]);
        swap_halves(pk5, pk7);
        union { u32 u[4]; short8 s8v; } ua, ub;
        ua.u[0] = pk0; ua.u[1] = pk1; ua.u[2] = pk2; ua.u[3] = pk3;
        ub.u[0] = pk4; ub.u[1] = pk5; ub.u[2] = pk6; ub.u[3] = pk7;
        const short8 pa0 = ua.s8v, pa1 = ub.s8v;
        // ---- PV: O^T[d][q] += V^T x P^T ----
#pragma unroll
        for (int db = 0; db < 4; ++db) {
            short8 vf0 = ld8(vb + (size_t)(db * 32) * SEQ + kv0);
            acco[db] = __builtin_amdgcn_mfma_f32_32x32x16_bf16(vf0, pa0, acco[db], 0, 0, 0);
            short8 vf1 = ld8(vb + (size_t)(db * 32) * SEQ + kv0 + 16);
            acco[db] = __builtin_amdgcn_mfma_f32_32x32x16_bf16(vf1, pa1, acco[db], 0, 0, 0);
        }
    }

    // ---- write partials (transposed, coalesced over q) ----
    float* pt = pacc + (size_t)(s * T32 + t32) * 128 * 32;
#pragma unroll
    for (int db = 0; db < 4; ++db)
#pragma unroll
        for (int r = 0; r < 16; ++r) {
            const int dloc = db * 32 + (r & 3) + 8 * (r >> 2) + 4 * hih;
            pt[(size_t)dloc * 32 + l31] = acco[db][r];
        }
    if (lane < 32) { pm[mlbase + l31] = m_r; pl[mlbase + l31] = l_r; }
}

// ---------------------------------------------------------------------------
// Combine NS partials per 32-row tile; LDS transpose for coalesced output.
// ---------------------------------------------------------------------------
__global__ __launch_bounds__(256) void combine_kernel(
    const float* __restrict__ pacc, const float* __restrict__ pm,
    const float* __restrict__ pl, float* __restrict__ out)
{
    __shared__ float wlds[NS][32];
    __shared__ float tlds[128][33];
    const int t32 = blockIdx.x;
    const int tid = threadIdx.x;

    if (tid < 32) {
        const int q = tid;
        float ms[NS], ls[NS];
        float M = -3.0e38f;
#pragma unroll
        for (int s = 0; s < NS; ++s) {
            ms[s] = pm[(size_t)(s * T32 + t32) * 32 + q];
            ls[s] = pl[(size_t)(s * T32 + t32) * 32 + q];
            M = fmaxf(M, ms[s]);
        }
        float w[NS], den = 0.f;
#pragma unroll
        for (int s = 0; s < NS; ++s) { w[s] = __expf(ms[s] - M); den += w[s] * ls[s]; }
        const float inv = 1.f / den;
#pragma unroll
        for (int s = 0; s < NS; ++s) wlds[s][q] = w[s] * inv;
    }
    __syncthreads();

#pragma unroll
    for (int rep = 0; rep < 16; ++rep) {
        const int flat = rep * 256 + tid;
        const int d = flat >> 5, q = flat & 31;
        float acc = 0.f;
#pragma unroll
        for (int s = 0; s < NS; ++s)
            acc += wlds[s][q] * pacc[((size_t)(s * T32 + t32) * 128 + d) * 32 + q];
        tlds[d][q] = acc;
    }
    __syncthreads();

    const size_t row0 = (size_t)t32 * 32;
#pragma unroll
    for (int rep = 0; rep < 16; ++rep) {
        const int flat = rep * 256 + tid;
        const int q = flat >> 7, d = flat & 127;
        out[(row0 + q) * 128 + d] = tlds[d][q];
    }
}

// ---------------------------------------------------------------------------
extern "C" void kernel_launch(void* const* d_in, const int* in_sizes, int n_in,
                              void* d_out, int out_size, void* d_ws, size_t ws_size,
                              hipStream_t stream)
{
    const float* x  = (const float*)d_in[0];
    const float* Wq = (const float*)d_in[1];
    const float* Wk = (const float*)d_in[2];
    const float* Wv = (const float*)d_in[3];
    float* out = (float*)d_out;

    unsigned short* wbf = (unsigned short*)d_ws;                 // 384*1024 bf16
    unsigned short* qo  = wbf + (size_t)384 * DMODEL;            // 16384*128
    unsigned short* ko  = qo  + (size_t)MROWS * HDIM;
    unsigned short* vt  = ko  + (size_t)MROWS * HDIM;            // 4*128*4096
    float* pacc = (float*)(vt + (size_t)BATCH * HDIM * SEQ);     // NS*512*128*32 f32
    float* pm   = pacc + (size_t)NS * T32 * 128 * 32;
    float* pl   = pm   + (size_t)NS * T32 * 32;
    // total ~46.9 MB

    const int n8w3 = 3 * HDIM * DMODEL / 8;
    cvt_w_kernel<<<(n8w3 + 255) / 256, 256, 0, stream>>>(Wq, Wk, Wv, wbf);

    qkv_kernel<<<(MROWS / BM) * (384 / BN), 256, 0, stream>>>(x, wbf, qo, ko, vt);

    attn_kernel<<<T32 * NS, 64, 0, stream>>>(qo, ko, vt, pacc, pm, pl);

    combine_kernel<<<T32, 256, 0, stream>>>(pacc, pm, pl, out);
}